// Round 8
// baseline (258.882 us; speedup 1.0000x reference)
//
#include <hip/hip_runtime.h>
#include <math.h>

// HadamardProj: out[b,o] = -scale * (x[b]/(||x[b]||+eps)) . H[o,:] + bias[o]
// H[o,i] = (-1)^popcount(o&i), i<2048  =>  H row o == H row (o mod 2048)
// => y[b] = FWHT_2048(x[b]) (Sylvester), out[b,o] = -scale*inv_norm*y[o&2047] + bias[o]
//
// R8: occupancy experiment. R5 structure (register-resident FWHT, bias staged
// in LDS) but 512-thread blocks + __launch_bounds__(512,8): 8 waves share one
// 40 KB bias copy -> LDS fits 4 blocks/CU, VGPR capped at 64 -> 32 waves/CU
// (was 16). Tests whether TLP is the residual limiter (we're at 76% of copy
// BW; tuned norm kernels reach 86% at high occupancy).

typedef float f32x4 __attribute__((ext_vector_type(4)));

constexpr int N_IN  = 2048;    // 2^11
constexpr int N_OUT = 10000;
constexpr int WAVES_PER_BLOCK = 8;   // 512 threads

__global__ __launch_bounds__(512, 8) void fwht_proj_kernel(
    const float* __restrict__ x,
    const float* __restrict__ scale,
    const float* __restrict__ bias,
    float* __restrict__ out)
{
    __shared__ f32x4 biaslds[N_OUT / 4];   // 40,000 B; 4 blocks/CU

    // Stage bias once per block (amortized over 8 rows)
    {
        const f32x4* __restrict__ b4 = reinterpret_cast<const f32x4*>(bias);
        for (int i = threadIdx.x; i < N_OUT / 4; i += 512)
            biaslds[i] = b4[i];
    }
    __syncthreads();

    const int wave = threadIdx.x >> 6;
    const int lane = threadIdx.x & 63;
    const size_t row = (size_t)blockIdx.x * WAVES_PER_BLOCK + wave;

    const float* __restrict__ xrow = x + row * N_IN;

    // Lane owns e = j*256 + lane*4 + c  (f32x4 coalesced loads, 1 KiB/instr)
    f32x4 v[8];
    float ss = 0.0f;
#pragma unroll
    for (int j = 0; j < 8; ++j) {
        v[j] = *reinterpret_cast<const f32x4*>(xrow + (j << 8) + (lane << 2));
        ss = fmaf(v[j].x, v[j].x, ss);
        ss = fmaf(v[j].y, v[j].y, ss);
        ss = fmaf(v[j].z, v[j].z, ss);
        ss = fmaf(v[j].w, v[j].w, ss);
    }
#pragma unroll
    for (int m = 1; m < 64; m <<= 1)
        ss += __shfl_xor(ss, m, 64);
    const float inv = 1.0f / (sqrtf(ss) + 1e-8f);  // matches x/(norm+eps)

    // FWHT stages h=1,2: inside each float4
#pragma unroll
    for (int j = 0; j < 8; ++j) {
        const f32x4 a = v[j];
        f32x4 t;
        t.x = a.x + a.y;  t.y = a.x - a.y;
        t.z = a.z + a.w;  t.w = a.z - a.w;
        f32x4 u;
        u.x = t.x + t.z;  u.y = t.y + t.w;
        u.z = t.x - t.z;  u.w = t.y - t.w;
        v[j] = u;
    }
    // Stages h=4..128: cross-lane (lane xor 1..32)
#pragma unroll
    for (int m = 1; m <= 32; m <<= 1) {
        const bool lo = (lane & m) == 0;
#pragma unroll
        for (int j = 0; j < 8; ++j) {
            f32x4 o;
            o.x = __shfl_xor(v[j].x, m, 64);
            o.y = __shfl_xor(v[j].y, m, 64);
            o.z = __shfl_xor(v[j].z, m, 64);
            o.w = __shfl_xor(v[j].w, m, 64);
            v[j] = lo ? (v[j] + o) : (o - v[j]);
        }
    }
    // Stages h=256,512,1024: register index xor 1,2,4
#pragma unroll
    for (int jm = 1; jm <= 4; jm <<= 1) {
#pragma unroll
        for (int j = 0; j < 8; ++j) {
            if ((j & jm) == 0) {
                const f32x4 a = v[j], b = v[j ^ jm];
                v[j]      = a + b;
                v[j ^ jm] = a - b;
            }
        }
    }

    const float s = -scale[0] * inv;   // fold norm + negated scale
    float* __restrict__ orow = out + row * N_OUT;

    // Register-resident epilogue; bias from LDS (b128, conflict-free).
#pragma unroll
    for (int w = 0; w < 4; ++w) {
#pragma unroll 2
        for (int j = 0; j < 8; ++j) {
            const int o = (w << 11) + (j << 8) + (lane << 2);
            const f32x4 b = biaslds[(w << 9) + (j << 6) + lane];
            f32x4 rv;
            rv.x = fmaf(s, v[j].x, b.x);
            rv.y = fmaf(s, v[j].y, b.y);
            rv.z = fmaf(s, v[j].z, b.z);
            rv.w = fmaf(s, v[j].w, b.w);
            *reinterpret_cast<f32x4*>(orow + o) = rv;
        }
    }
    // Partial window w=4: j=0..6 full, j=7 lanes 0..3
#pragma unroll 2
    for (int j = 0; j < 7; ++j) {
        const int o = 8192 + (j << 8) + (lane << 2);
        const f32x4 b = biaslds[2048 + (j << 6) + lane];
        f32x4 rv;
        rv.x = fmaf(s, v[j].x, b.x);
        rv.y = fmaf(s, v[j].y, b.y);
        rv.z = fmaf(s, v[j].z, b.z);
        rv.w = fmaf(s, v[j].w, b.w);
        *reinterpret_cast<f32x4*>(orow + o) = rv;
    }
    if (lane < 4) {
        const int o = 9984 + (lane << 2);
        const f32x4 b = biaslds[2496 + lane];
        f32x4 rv;
        rv.x = fmaf(s, v[7].x, b.x);
        rv.y = fmaf(s, v[7].y, b.y);
        rv.z = fmaf(s, v[7].z, b.z);
        rv.w = fmaf(s, v[7].w, b.w);
        *reinterpret_cast<f32x4*>(orow + o) = rv;
    }
}

extern "C" void kernel_launch(void* const* d_in, const int* in_sizes, int n_in,
                              void* d_out, int out_size, void* d_ws, size_t ws_size,
                              hipStream_t stream) {
    const float* x     = (const float*)d_in[0];
    // d_in[1] = proj: unused — Hadamard structure computed via FWHT
    const float* scale = (const float*)d_in[2];
    const float* bias  = (const float*)d_in[3];
    float* out = (float*)d_out;

    const int rows = in_sizes[0] / N_IN;            // 16384
    dim3 grid(rows / WAVES_PER_BLOCK), block(512);  // 2048 blocks
    hipLaunchKernelGGL(fwht_proj_kernel, grid, block, 0, stream,
                       x, scale, bias, out);
}

// Round 9
// 253.110 us; speedup vs baseline: 1.0228x; 1.0228x over previous
//
#include <hip/hip_runtime.h>
#include <math.h>

// HadamardProj: out[b,o] = -scale * (x[b]/(||x[b]||+eps)) . H[o,:] + bias[o]
// H[o,i] = (-1)^popcount(o&i), i<2048  =>  H row o == H row (o mod 2048)
// => y[b] = FWHT_2048(x[b]) (Sylvester), out[b,o] = -scale*inv_norm*y[o&2047] + bias[o]
//
// R9: clean occupancy test. R5 structure (register-resident FWHT, LDS bias),
// but bias stored as bf16 in LDS (20,000 B; rounding <=1.5e-5, far under the
// 1.28e-3 threshold) so LDS allows 8 blocks/CU, and __launch_bounds__(256,6)
// caps VGPR at ~85 -> 6 waves/SIMD = 24 waves/CU (was 16). Single lever.

typedef float f32x4 __attribute__((ext_vector_type(4)));
typedef unsigned short u16x4 __attribute__((ext_vector_type(4)));

constexpr int N_IN  = 2048;    // 2^11
constexpr int N_OUT = 10000;
constexpr int WAVES_PER_BLOCK = 4;

__global__ __launch_bounds__(256, 6) void fwht_proj_kernel(
    const float* __restrict__ x,
    const float* __restrict__ scale,
    const float* __restrict__ bias,
    float* __restrict__ out)
{
    __shared__ unsigned short biaslds[N_OUT];   // bf16: 20,000 B

    // Stage bias once per block, f32 -> bf16 (round-to-nearest-even)
    {
        const f32x4* __restrict__ b4 = reinterpret_cast<const f32x4*>(bias);
        for (int i = threadIdx.x; i < N_OUT / 4; i += 256) {
            const f32x4 b = b4[i];
            u16x4 h;
            unsigned u;
            u = __float_as_uint(b.x); h.x = (unsigned short)((u + 0x7FFF + ((u >> 16) & 1)) >> 16);
            u = __float_as_uint(b.y); h.y = (unsigned short)((u + 0x7FFF + ((u >> 16) & 1)) >> 16);
            u = __float_as_uint(b.z); h.z = (unsigned short)((u + 0x7FFF + ((u >> 16) & 1)) >> 16);
            u = __float_as_uint(b.w); h.w = (unsigned short)((u + 0x7FFF + ((u >> 16) & 1)) >> 16);
            *reinterpret_cast<u16x4*>(&biaslds[i << 2]) = h;
        }
    }
    __syncthreads();

    const int wave = threadIdx.x >> 6;
    const int lane = threadIdx.x & 63;
    const size_t row = (size_t)blockIdx.x * WAVES_PER_BLOCK + wave;

    const float* __restrict__ xrow = x + row * N_IN;

    // Lane owns e = j*256 + lane*4 + c  (f32x4 coalesced loads)
    f32x4 v[8];
    float ss = 0.0f;
#pragma unroll
    for (int j = 0; j < 8; ++j) {
        v[j] = *reinterpret_cast<const f32x4*>(xrow + (j << 8) + (lane << 2));
        ss = fmaf(v[j].x, v[j].x, ss);
        ss = fmaf(v[j].y, v[j].y, ss);
        ss = fmaf(v[j].z, v[j].z, ss);
        ss = fmaf(v[j].w, v[j].w, ss);
    }
#pragma unroll
    for (int m = 1; m < 64; m <<= 1)
        ss += __shfl_xor(ss, m, 64);
    const float inv = 1.0f / (sqrtf(ss) + 1e-8f);  // matches x/(norm+eps)

    // FWHT stages h=1,2: inside each float4
#pragma unroll
    for (int j = 0; j < 8; ++j) {
        const f32x4 a = v[j];
        f32x4 t;
        t.x = a.x + a.y;  t.y = a.x - a.y;
        t.z = a.z + a.w;  t.w = a.z - a.w;
        f32x4 u;
        u.x = t.x + t.z;  u.y = t.y + t.w;
        u.z = t.x - t.z;  u.w = t.y - t.w;
        v[j] = u;
    }
    // Stages h=4..128: cross-lane (lane xor 1..32)
#pragma unroll
    for (int m = 1; m <= 32; m <<= 1) {
        const bool lo = (lane & m) == 0;
#pragma unroll
        for (int j = 0; j < 8; ++j) {
            f32x4 o;
            o.x = __shfl_xor(v[j].x, m, 64);
            o.y = __shfl_xor(v[j].y, m, 64);
            o.z = __shfl_xor(v[j].z, m, 64);
            o.w = __shfl_xor(v[j].w, m, 64);
            v[j] = lo ? (v[j] + o) : (o - v[j]);
        }
    }
    // Stages h=256,512,1024: register index xor 1,2,4
#pragma unroll
    for (int jm = 1; jm <= 4; jm <<= 1) {
#pragma unroll
        for (int j = 0; j < 8; ++j) {
            if ((j & jm) == 0) {
                const f32x4 a = v[j], b = v[j ^ jm];
                v[j]      = a + b;
                v[j ^ jm] = a - b;
            }
        }
    }

    const float s = -scale[0] * inv;   // fold norm + negated scale
    float* __restrict__ orow = out + row * N_OUT;

    // Register-resident epilogue; bf16 bias from LDS (ds_read_b64, 2-way = free).
#pragma unroll
    for (int w = 0; w < 4; ++w) {
#pragma unroll 2
        for (int j = 0; j < 8; ++j) {
            const int o = (w << 11) + (j << 8) + (lane << 2);
            const u16x4 h = *reinterpret_cast<const u16x4*>(&biaslds[o]);
            f32x4 rv;
            rv.x = fmaf(s, v[j].x, __uint_as_float((unsigned)h.x << 16));
            rv.y = fmaf(s, v[j].y, __uint_as_float((unsigned)h.y << 16));
            rv.z = fmaf(s, v[j].z, __uint_as_float((unsigned)h.z << 16));
            rv.w = fmaf(s, v[j].w, __uint_as_float((unsigned)h.w << 16));
            *reinterpret_cast<f32x4*>(orow + o) = rv;
        }
    }
    // Partial window w=4: j=0..6 full, j=7 lanes 0..3
#pragma unroll 2
    for (int j = 0; j < 7; ++j) {
        const int o = 8192 + (j << 8) + (lane << 2);
        const u16x4 h = *reinterpret_cast<const u16x4*>(&biaslds[o]);
        f32x4 rv;
        rv.x = fmaf(s, v[j].x, __uint_as_float((unsigned)h.x << 16));
        rv.y = fmaf(s, v[j].y, __uint_as_float((unsigned)h.y << 16));
        rv.z = fmaf(s, v[j].z, __uint_as_float((unsigned)h.z << 16));
        rv.w = fmaf(s, v[j].w, __uint_as_float((unsigned)h.w << 16));
        *reinterpret_cast<f32x4*>(orow + o) = rv;
    }
    if (lane < 4) {
        const int o = 9984 + (lane << 2);
        const u16x4 h = *reinterpret_cast<const u16x4*>(&biaslds[o]);
        f32x4 rv;
        rv.x = fmaf(s, v[7].x, __uint_as_float((unsigned)h.x << 16));
        rv.y = fmaf(s, v[7].y, __uint_as_float((unsigned)h.y << 16));
        rv.z = fmaf(s, v[7].z, __uint_as_float((unsigned)h.z << 16));
        rv.w = fmaf(s, v[7].w, __uint_as_float((unsigned)h.w << 16));
        *reinterpret_cast<f32x4*>(orow + o) = rv;
    }
}

extern "C" void kernel_launch(void* const* d_in, const int* in_sizes, int n_in,
                              void* d_out, int out_size, void* d_ws, size_t ws_size,
                              hipStream_t stream) {
    const float* x     = (const float*)d_in[0];
    // d_in[1] = proj: unused — Hadamard structure computed via FWHT
    const float* scale = (const float*)d_in[2];
    const float* bias  = (const float*)d_in[3];
    float* out = (float*)d_out;

    const int rows = in_sizes[0] / N_IN;            // 16384
    dim3 grid(rows / WAVES_PER_BLOCK), block(256);  // 4096 blocks
    hipLaunchKernelGGL(fwht_proj_kernel, grid, block, 0, stream,
                       x, scale, bias, out);
}

// Round 10
// 160.288 us; speedup vs baseline: 1.6151x; 1.5791x over previous
//
#include <hip/hip_runtime.h>
#include <math.h>

// HadamardProj: out[b,o] = -scale * (x[b]/(||x[b]||+eps)) . H[o,:] + bias[o]
// H[o,i] = (-1)^popcount(o&i), i<2048  =>  H row o == H row (o mod 2048)
// => y[b] = FWHT_2048(x[b]) (Sylvester), out[b,o] = -scale*inv_norm*y[o&2047] + bias[o]
//
// R10: replace the 6 cross-lane shuffle stages (192 ds_swizzle/row) with ONE
// wave-private LDS transpose (32 ds_write_b32 + 8 ds_read_b128) + a single
// xor-1 shuffle stage. Element bits e[10:0]; stage h flips bit log2(h).
//   Layout A (load):  e = j*256 + lane*4 + c  -> bits {0,1}=c, {7:2}=lane, {10:8}=j
//     A-stages: h=1,2 (in-vec), h=256,512,1024 (reg xor)      covers {0,1,8,9,10}
//   Transpose sigma: slot a[1:0]=e[3:2], a[4:2]=e[6:4], a[5]=e[7], a[6]=e[1],
//                    a[9:7]=e[10:8], a[10]=e[0]
//   Layout B (read): a = lane*32 + j*4 + c -> B-stages: h=4,8 (in-vec),
//     h=16,32,64 (reg xor), h=128 = lane xor 1 (one shuffle stage). covers {2..7}
// All LDS accesses XOR-swizzled (bits[7:5]^[10:8] -> bits[4:2]): every phase <=2-way.

typedef float f32x4 __attribute__((ext_vector_type(4)));

constexpr int N_IN  = 2048;   // 2^11
constexpr int N_OUT = 10000;

__device__ __forceinline__ int swz(int a) {   // float-index swizzle, involution
    return a ^ ((((a >> 5) ^ (a >> 8)) & 7) << 2);
}

__global__ __launch_bounds__(256, 4) void fwht_proj_kernel(
    const float* __restrict__ x,
    const float* __restrict__ scale,
    const float* __restrict__ bias,
    float* __restrict__ out)
{
    __shared__ float buf[4][N_IN];   // 32 KiB: one private 8 KiB buffer per wave

    const int wave = threadIdx.x >> 6;
    const int lane = threadIdx.x & 63;
    float* __restrict__ my = buf[wave];
    const size_t row = (size_t)blockIdx.x * 4 + wave;   // rows % 4 == 0
    const float* __restrict__ xrow = x + row * N_IN;

    // ---- load (layout A) + sum of squares ----
    f32x4 v[8];
    float ss = 0.0f;
#pragma unroll
    for (int j = 0; j < 8; ++j) {
        v[j] = *reinterpret_cast<const f32x4*>(xrow + (j << 8) + (lane << 2));
        ss = fmaf(v[j].x, v[j].x, ss);
        ss = fmaf(v[j].y, v[j].y, ss);
        ss = fmaf(v[j].z, v[j].z, ss);
        ss = fmaf(v[j].w, v[j].w, ss);
    }
#pragma unroll
    for (int m = 1; m < 64; m <<= 1)
        ss += __shfl_xor(ss, m, 64);
    const float inv = 1.0f / (sqrtf(ss) + 1e-8f);   // matches x/(norm+eps)

    // ---- A-stages: bits 0,1 (inside each float4) ----
#pragma unroll
    for (int j = 0; j < 8; ++j) {
        const f32x4 a = v[j];
        f32x4 t;
        t.x = a.x + a.y;  t.y = a.x - a.y;
        t.z = a.z + a.w;  t.w = a.z - a.w;
        f32x4 u;
        u.x = t.x + t.z;  u.y = t.y + t.w;
        u.z = t.x - t.z;  u.w = t.y - t.w;
        v[j] = u;
    }
    // ---- A-stages: bits 8,9,10 (register index xor 1,2,4) ----
#pragma unroll
    for (int jm = 1; jm <= 4; jm <<= 1) {
#pragma unroll
        for (int j = 0; j < 8; ++j) {
            if ((j & jm) == 0) {
                const f32x4 a = v[j], b = v[j ^ jm];
                v[j]      = a + b;
                v[j ^ jm] = a - b;
            }
        }
    }

    // ---- transpose write: slot sigma(e) = lane + c1*64 + j*128 + c0*1024 ----
    // (banks: a[4:0]=lane[4:0] -> 2-way before swizzle; swz keeps <=2-way)
#pragma unroll
    for (int j = 0; j < 8; ++j) {
        my[swz(lane + (j << 7)       )] = v[j].x;   // c=0
        my[swz(lane + (j << 7) + 1024)] = v[j].y;   // c=1 (bit0 -> a[10])
        my[swz(lane + (j << 7) +   64)] = v[j].z;   // c=2 (bit1 -> a[6])
        my[swz(lane + (j << 7) + 1088)] = v[j].w;   // c=3
    }
    asm volatile("s_waitcnt lgkmcnt(0)" ::: "memory");
    // ---- transposed read (layout B): a = lane*32 + j*4 ----
#pragma unroll
    for (int j = 0; j < 8; ++j)
        v[j] = *reinterpret_cast<const f32x4*>(my + swz((lane << 5) + (j << 2)));

    // ---- B-stage bit 7: partner = lane xor 1 (single shuffle stage) ----
    {
        const bool lo = (lane & 1) == 0;
#pragma unroll
        for (int j = 0; j < 8; ++j) {
            f32x4 p;
            p.x = __shfl_xor(v[j].x, 1, 64);
            p.y = __shfl_xor(v[j].y, 1, 64);
            p.z = __shfl_xor(v[j].z, 1, 64);
            p.w = __shfl_xor(v[j].w, 1, 64);
            v[j] = lo ? (v[j] + p) : (p - v[j]);
        }
    }
    // ---- B-stages: bits 2,3 (inside each float4) ----
#pragma unroll
    for (int j = 0; j < 8; ++j) {
        const f32x4 a = v[j];
        f32x4 t;
        t.x = a.x + a.y;  t.y = a.x - a.y;
        t.z = a.z + a.w;  t.w = a.z - a.w;
        f32x4 u;
        u.x = t.x + t.z;  u.y = t.y + t.w;
        u.z = t.x - t.z;  u.w = t.y - t.w;
        v[j] = u;
    }
    // ---- B-stages: bits 4,5,6 (register index xor 1,2,4) ----
#pragma unroll
    for (int jm = 1; jm <= 4; jm <<= 1) {
#pragma unroll
        for (int j = 0; j < 8; ++j) {
            if ((j & jm) == 0) {
                const f32x4 a = v[j], b = v[j ^ jm];
                v[j]      = a + b;
                v[j ^ jm] = a - b;
            }
        }
    }

    // ---- y write-back at plain element index e (swizzled) ----
    // e = 4c + 16j + 128*lane[0] + 2*lane[1] + 256*lane[2] + 512*lane[3]
    //     + 1024*lane[4] + lane[5]
    const int ybase = ((lane & 1) << 7) | (lane & 2) | ((lane & 28) << 6) | ((lane >> 5) & 1);
#pragma unroll
    for (int j = 0; j < 8; ++j) {
        my[swz(ybase + (j << 4)     )] = v[j].x;
        my[swz(ybase + (j << 4) +  4)] = v[j].y;
        my[swz(ybase + (j << 4) +  8)] = v[j].z;
        my[swz(ybase + (j << 4) + 12)] = v[j].w;
    }
    asm volatile("s_waitcnt lgkmcnt(0)" ::: "memory");

    // ---- epilogue: y from LDS (swizzled linear), bias from global (L2-hot) ----
    const float s = -scale[0] * inv;
    float* __restrict__ orow = out + row * N_OUT;

    int yo[8];                       // statically indexed after unroll
#pragma unroll
    for (int j = 0; j < 8; ++j)
        yo[j] = swz((j << 8) + (lane << 2));

#pragma unroll
    for (int w = 0; w < 4; ++w) {
#pragma unroll
        for (int j = 0; j < 8; ++j) {
            const int o = (w << 11) + (j << 8) + (lane << 2);
            const f32x4 y = *reinterpret_cast<const f32x4*>(my + yo[j]);
            const f32x4 b = *reinterpret_cast<const f32x4*>(bias + o);
            f32x4 r;
            r.x = fmaf(s, y.x, b.x);
            r.y = fmaf(s, y.y, b.y);
            r.z = fmaf(s, y.z, b.z);
            r.w = fmaf(s, y.w, b.w);
            *reinterpret_cast<f32x4*>(orow + o) = r;
        }
    }
    // partial window w=4: j=0..6 full, j=7 lanes 0..3
#pragma unroll
    for (int j = 0; j < 7; ++j) {
        const int o = 8192 + (j << 8) + (lane << 2);
        const f32x4 y = *reinterpret_cast<const f32x4*>(my + yo[j]);
        const f32x4 b = *reinterpret_cast<const f32x4*>(bias + o);
        f32x4 r;
        r.x = fmaf(s, y.x, b.x);
        r.y = fmaf(s, y.y, b.y);
        r.z = fmaf(s, y.z, b.z);
        r.w = fmaf(s, y.w, b.w);
        *reinterpret_cast<f32x4*>(orow + o) = r;
    }
    if (lane < 4) {
        const int o = 9984 + (lane << 2);
        const f32x4 y = *reinterpret_cast<const f32x4*>(my + yo[7]);
        const f32x4 b = *reinterpret_cast<const f32x4*>(bias + o);
        f32x4 r;
        r.x = fmaf(s, y.x, b.x);
        r.y = fmaf(s, y.y, b.y);
        r.z = fmaf(s, y.z, b.z);
        r.w = fmaf(s, y.w, b.w);
        *reinterpret_cast<f32x4*>(orow + o) = r;
    }
}

extern "C" void kernel_launch(void* const* d_in, const int* in_sizes, int n_in,
                              void* d_out, int out_size, void* d_ws, size_t ws_size,
                              hipStream_t stream) {
    const float* x     = (const float*)d_in[0];
    // d_in[1] = proj: unused — Hadamard structure computed via FWHT
    const float* scale = (const float*)d_in[2];
    const float* bias  = (const float*)d_in[3];
    float* out = (float*)d_out;

    const int rows = in_sizes[0] / N_IN;            // 16384
    dim3 grid(rows / 4), block(256);                // 4096 blocks
    hipLaunchKernelGGL(fwht_proj_kernel, grid, block, 0, stream,
                       x, scale, bias, out);
}

// Round 11
// 160.208 us; speedup vs baseline: 1.6159x; 1.0005x over previous
//
#include <hip/hip_runtime.h>
#include <math.h>

// HadamardProj: out[b,o] = -scale * (x[b]/(||x[b]||+eps)) . H[o,:] + bias[o]
// H[o,i] = (-1)^popcount(o&i), i<2048  =>  H row o == H row (o mod 2048)
// => y[b] = FWHT_2048(x[b]) (Sylvester), out[b,o] = -scale*inv_norm*y[o&2047] + bias[o]
//
// R10: replace the 6 cross-lane shuffle stages (192 ds_swizzle/row) with ONE
// wave-private LDS transpose (32 ds_write_b32 + 8 ds_read_b128) + a single
// xor-1 shuffle stage. Element bits e[10:0]; stage h flips bit log2(h).
//   Layout A (load):  e = j*256 + lane*4 + c  -> bits {0,1}=c, {7:2}=lane, {10:8}=j
//     A-stages: h=1,2 (in-vec), h=256,512,1024 (reg xor)      covers {0,1,8,9,10}
//   Transpose sigma: slot a[1:0]=e[3:2], a[4:2]=e[6:4], a[5]=e[7], a[6]=e[1],
//                    a[9:7]=e[10:8], a[10]=e[0]
//   Layout B (read): a = lane*32 + j*4 + c -> B-stages: h=4,8 (in-vec),
//     h=16,32,64 (reg xor), h=128 = lane xor 1 (one shuffle stage). covers {2..7}
// All LDS accesses XOR-swizzled (bits[7:5]^[10:8] -> bits[4:2]): every phase <=2-way.

typedef float f32x4 __attribute__((ext_vector_type(4)));

constexpr int N_IN  = 2048;   // 2^11
constexpr int N_OUT = 10000;

__device__ __forceinline__ int swz(int a) {   // float-index swizzle, involution
    return a ^ ((((a >> 5) ^ (a >> 8)) & 7) << 2);
}

__global__ __launch_bounds__(256, 4) void fwht_proj_kernel(
    const float* __restrict__ x,
    const float* __restrict__ scale,
    const float* __restrict__ bias,
    float* __restrict__ out)
{
    __shared__ float buf[4][N_IN];   // 32 KiB: one private 8 KiB buffer per wave

    const int wave = threadIdx.x >> 6;
    const int lane = threadIdx.x & 63;
    float* __restrict__ my = buf[wave];
    const size_t row = (size_t)blockIdx.x * 4 + wave;   // rows % 4 == 0
    const float* __restrict__ xrow = x + row * N_IN;

    // ---- load (layout A) + sum of squares ----
    f32x4 v[8];
    float ss = 0.0f;
#pragma unroll
    for (int j = 0; j < 8; ++j) {
        v[j] = *reinterpret_cast<const f32x4*>(xrow + (j << 8) + (lane << 2));
        ss = fmaf(v[j].x, v[j].x, ss);
        ss = fmaf(v[j].y, v[j].y, ss);
        ss = fmaf(v[j].z, v[j].z, ss);
        ss = fmaf(v[j].w, v[j].w, ss);
    }
#pragma unroll
    for (int m = 1; m < 64; m <<= 1)
        ss += __shfl_xor(ss, m, 64);
    const float inv = 1.0f / (sqrtf(ss) + 1e-8f);   // matches x/(norm+eps)

    // ---- A-stages: bits 0,1 (inside each float4) ----
#pragma unroll
    for (int j = 0; j < 8; ++j) {
        const f32x4 a = v[j];
        f32x4 t;
        t.x = a.x + a.y;  t.y = a.x - a.y;
        t.z = a.z + a.w;  t.w = a.z - a.w;
        f32x4 u;
        u.x = t.x + t.z;  u.y = t.y + t.w;
        u.z = t.x - t.z;  u.w = t.y - t.w;
        v[j] = u;
    }
    // ---- A-stages: bits 8,9,10 (register index xor 1,2,4) ----
#pragma unroll
    for (int jm = 1; jm <= 4; jm <<= 1) {
#pragma unroll
        for (int j = 0; j < 8; ++j) {
            if ((j & jm) == 0) {
                const f32x4 a = v[j], b = v[j ^ jm];
                v[j]      = a + b;
                v[j ^ jm] = a - b;
            }
        }
    }

    // ---- transpose write: slot sigma(e) = lane + c1*64 + j*128 + c0*1024 ----
    // (banks: a[4:0]=lane[4:0] -> 2-way before swizzle; swz keeps <=2-way)
#pragma unroll
    for (int j = 0; j < 8; ++j) {
        my[swz(lane + (j << 7)       )] = v[j].x;   // c=0
        my[swz(lane + (j << 7) + 1024)] = v[j].y;   // c=1 (bit0 -> a[10])
        my[swz(lane + (j << 7) +   64)] = v[j].z;   // c=2 (bit1 -> a[6])
        my[swz(lane + (j << 7) + 1088)] = v[j].w;   // c=3
    }
    asm volatile("s_waitcnt lgkmcnt(0)" ::: "memory");
    // ---- transposed read (layout B): a = lane*32 + j*4 ----
#pragma unroll
    for (int j = 0; j < 8; ++j)
        v[j] = *reinterpret_cast<const f32x4*>(my + swz((lane << 5) + (j << 2)));

    // ---- B-stage bit 7: partner = lane xor 1 (single shuffle stage) ----
    {
        const bool lo = (lane & 1) == 0;
#pragma unroll
        for (int j = 0; j < 8; ++j) {
            f32x4 p;
            p.x = __shfl_xor(v[j].x, 1, 64);
            p.y = __shfl_xor(v[j].y, 1, 64);
            p.z = __shfl_xor(v[j].z, 1, 64);
            p.w = __shfl_xor(v[j].w, 1, 64);
            v[j] = lo ? (v[j] + p) : (p - v[j]);
        }
    }
    // ---- B-stages: bits 2,3 (inside each float4) ----
#pragma unroll
    for (int j = 0; j < 8; ++j) {
        const f32x4 a = v[j];
        f32x4 t;
        t.x = a.x + a.y;  t.y = a.x - a.y;
        t.z = a.z + a.w;  t.w = a.z - a.w;
        f32x4 u;
        u.x = t.x + t.z;  u.y = t.y + t.w;
        u.z = t.x - t.z;  u.w = t.y - t.w;
        v[j] = u;
    }
    // ---- B-stages: bits 4,5,6 (register index xor 1,2,4) ----
#pragma unroll
    for (int jm = 1; jm <= 4; jm <<= 1) {
#pragma unroll
        for (int j = 0; j < 8; ++j) {
            if ((j & jm) == 0) {
                const f32x4 a = v[j], b = v[j ^ jm];
                v[j]      = a + b;
                v[j ^ jm] = a - b;
            }
        }
    }

    // ---- y write-back at plain element index e (swizzled) ----
    // e = 4c + 16j + 128*lane[0] + 2*lane[1] + 256*lane[2] + 512*lane[3]
    //     + 1024*lane[4] + lane[5]
    const int ybase = ((lane & 1) << 7) | (lane & 2) | ((lane & 28) << 6) | ((lane >> 5) & 1);
#pragma unroll
    for (int j = 0; j < 8; ++j) {
        my[swz(ybase + (j << 4)     )] = v[j].x;
        my[swz(ybase + (j << 4) +  4)] = v[j].y;
        my[swz(ybase + (j << 4) +  8)] = v[j].z;
        my[swz(ybase + (j << 4) + 12)] = v[j].w;
    }
    asm volatile("s_waitcnt lgkmcnt(0)" ::: "memory");

    // ---- epilogue: y from LDS (swizzled linear), bias from global (L2-hot) ----
    const float s = -scale[0] * inv;
    float* __restrict__ orow = out + row * N_OUT;

    int yo[8];                       // statically indexed after unroll
#pragma unroll
    for (int j = 0; j < 8; ++j)
        yo[j] = swz((j << 8) + (lane << 2));

#pragma unroll
    for (int w = 0; w < 4; ++w) {
#pragma unroll
        for (int j = 0; j < 8; ++j) {
            const int o = (w << 11) + (j << 8) + (lane << 2);
            const f32x4 y = *reinterpret_cast<const f32x4*>(my + yo[j]);
            const f32x4 b = *reinterpret_cast<const f32x4*>(bias + o);
            f32x4 r;
            r.x = fmaf(s, y.x, b.x);
            r.y = fmaf(s, y.y, b.y);
            r.z = fmaf(s, y.z, b.z);
            r.w = fmaf(s, y.w, b.w);
            *reinterpret_cast<f32x4*>(orow + o) = r;
        }
    }
    // partial window w=4: j=0..6 full, j=7 lanes 0..3
#pragma unroll
    for (int j = 0; j < 7; ++j) {
        const int o = 8192 + (j << 8) + (lane << 2);
        const f32x4 y = *reinterpret_cast<const f32x4*>(my + yo[j]);
        const f32x4 b = *reinterpret_cast<const f32x4*>(bias + o);
        f32x4 r;
        r.x = fmaf(s, y.x, b.x);
        r.y = fmaf(s, y.y, b.y);
        r.z = fmaf(s, y.z, b.z);
        r.w = fmaf(s, y.w, b.w);
        *reinterpret_cast<f32x4*>(orow + o) = r;
    }
    if (lane < 4) {
        const int o = 9984 + (lane << 2);
        const f32x4 y = *reinterpret_cast<const f32x4*>(my + yo[7]);
        const f32x4 b = *reinterpret_cast<const f32x4*>(bias + o);
        f32x4 r;
        r.x = fmaf(s, y.x, b.x);
        r.y = fmaf(s, y.y, b.y);
        r.z = fmaf(s, y.z, b.z);
        r.w = fmaf(s, y.w, b.w);
        *reinterpret_cast<f32x4*>(orow + o) = r;
    }
}

extern "C" void kernel_launch(void* const* d_in, const int* in_sizes, int n_in,
                              void* d_out, int out_size, void* d_ws, size_t ws_size,
                              hipStream_t stream) {
    const float* x     = (const float*)d_in[0];
    // d_in[1] = proj: unused — Hadamard structure computed via FWHT
    const float* scale = (const float*)d_in[2];
    const float* bias  = (const float*)d_in[3];
    float* out = (float*)d_out;

    const int rows = in_sizes[0] / N_IN;            // 16384
    dim3 grid(rows / 4), block(256);                // 4096 blocks
    hipLaunchKernelGGL(fwht_proj_kernel, grid, block, 0, stream,
                       x, scale, bias, out);
}